// Round 1
// baseline (856.715 us; speedup 1.0000x reference)
//
#include <hip/hip_runtime.h>
#include <math.h>

// AutoCorrelation (Autoformer eval path), MI355X.
// B=8, L=4096, H=8, E=64 -> 512 channels; top_k = int(log(4096)) = 8.
// Pipeline:
//   k_fft_corr : per-channel 4096-pt FFT (q+ik packed), cross-spectrum summed
//                over channels into Sf[b][f] (atomic fp32, ws zeroed first)
//   k_ifft_topk: R = Re(FFT(conj(Sf)))/(L*CH); top-8 + softmax -> w,idx
//   k_gather   : out[b,t,:] = sum_i w_i * v[b,(t+idx_i)%L,:]  (float4)

namespace {
constexpr int LEN  = 4096;
constexpr int HALF = 2048;
constexpr int NCH  = 512;          // H*E
constexpr int NB   = 8;            // batch
constexpr int KTOP = 8;            // int(1.0 * log(4096))
constexpr int TPB  = 256;
constexpr int CPB  = 8;            // channels per block (kernel 1)
constexpr int GPB  = NCH / CPB;    // 64 groups per batch
constexpr size_t SF_BYTES = (size_t)NB * LEN * 2 * sizeof(float); // 262144
}

// Radix-2 Stockham DIF, N=4096, forward (e^{-i}), auto-sorting.
// Caller: bufA filled + __syncthreads() done. Result lands back in bufA
// (12 stages = even number of ping-pongs). tw[t] = exp(-2*pi*i*t/4096).
__device__ __forceinline__ void fft4096_fwd(float2* __restrict__ bufA,
                                            float2* __restrict__ bufB,
                                            const float2* __restrict__ tw,
                                            int tid)
{
  float2* src = bufA;
  float2* dst = bufB;
  #pragma unroll
  for (int st = 0; st < 12; ++st) {
    const int s = 1 << st;
    #pragma unroll
    for (int r = 0; r < HALF / TPB; ++r) {
      const int j = tid + r * TPB;
      const int q = j & (s - 1);         // j % s
      const int p = j >> st;             // j / s
      const float2 a = src[j];
      const float2 b = src[j + HALF];
      const float2 w = tw[j - q];        // tw[p*s]
      const float dx = a.x - b.x, dy = a.y - b.y;
      const int o0 = j + s * p;          // q + 2*s*p
      dst[o0]     = make_float2(a.x + b.x, a.y + b.y);
      dst[o0 + s] = make_float2(dx * w.x - dy * w.y, dx * w.y + dy * w.x);
    }
    __syncthreads();
    float2* t_ = src; src = dst; dst = t_;
  }
}

__global__ __launch_bounds__(TPB) void k_fft_corr(
    const float* __restrict__ qg, const float* __restrict__ kg,
    float* __restrict__ Sf)                     // [NB][LEN][2]
{
  __shared__ float2 bufA[LEN];
  __shared__ float2 bufB[LEN];
  __shared__ float2 tw[HALF];
  const int tid = threadIdx.x;
  const int b   = blockIdx.x / GPB;
  const int g   = blockIdx.x % GPB;
  const int ch0 = g * CPB;

  for (int t = tid; t < HALF; t += TPB) {
    float s, c;
    __sincosf((float)t * (float)(-2.0 * M_PI / 4096.0), &s, &c);
    tw[t] = make_float2(c, s);
  }

  float2 acc[LEN / TPB];                        // 16 bins/thread, registers
  #pragma unroll
  for (int r = 0; r < LEN / TPB; ++r) acc[r] = make_float2(0.f, 0.f);

  const size_t base = (size_t)b * LEN * NCH;
  for (int cc = 0; cc < CPB; ++cc) {
    const int ch = ch0 + cc;
    __syncthreads();                            // prev P-read done; tw ready
    #pragma unroll
    for (int r = 0; r < LEN / TPB; ++r) {
      const int t = tid + r * TPB;
      const size_t idx = base + (size_t)t * NCH + ch;
      bufA[t] = make_float2(qg[idx], kg[idx]);  // z = q + i*k
    }
    __syncthreads();
    fft4096_fwd(bufA, bufB, tw, tid);
    // P[f] = Qf*conj(Kf) = (i/4)*(A+B)*conj(A-B),
    // A = Z[f], B = conj(Z[(N-f)%N])
    #pragma unroll
    for (int r = 0; r < LEN / TPB; ++r) {
      const int f = tid + r * TPB;
      const float2 A  = bufA[f];
      float2 Bv = bufA[(LEN - f) & (LEN - 1)];
      Bv.y = -Bv.y;
      const float Sx = A.x + Bv.x, Sy = A.y + Bv.y;
      const float Dx = A.x - Bv.x, Dy = -(A.y - Bv.y); // conj(A-B)
      const float Mx = Sx * Dx - Sy * Dy;
      const float My = Sx * Dy + Sy * Dx;
      acc[r].x += -0.25f * My;                  // *(i/4)
      acc[r].y +=  0.25f * Mx;
    }
  }
  float* dstp = Sf + (size_t)b * LEN * 2;
  #pragma unroll
  for (int r = 0; r < LEN / TPB; ++r) {
    const int f = tid + r * TPB;
    atomicAdd(&dstp[2 * f],     acc[r].x);
    atomicAdd(&dstp[2 * f + 1], acc[r].y);
  }
}

__global__ __launch_bounds__(TPB) void k_ifft_topk(
    const float* __restrict__ Sf,               // [NB][LEN][2]
    float* __restrict__ wout, int* __restrict__ iout)
{
  __shared__ float2 bufA[LEN];
  __shared__ float2 bufB[LEN];
  __shared__ float2 tw[HALF];
  __shared__ float  R[LEN];
  __shared__ float  rv[TPB];
  __shared__ int    ri[TPB];
  __shared__ float  topv[KTOP];
  __shared__ int    topi[KTOP];
  const int tid = threadIdx.x;
  const int b   = blockIdx.x;

  for (int t = tid; t < HALF; t += TPB) {
    float s, c;
    __sincosf((float)t * (float)(-2.0 * M_PI / 4096.0), &s, &c);
    tw[t] = make_float2(c, s);
  }
  const float* srcp = Sf + (size_t)b * LEN * 2;
  for (int r = 0; r < LEN / TPB; ++r) {
    const int f = tid + r * TPB;
    bufA[f] = make_float2(srcp[2 * f], -srcp[2 * f + 1]);  // conj(P)
  }
  __syncthreads();
  fft4096_fwd(bufA, bufB, tw, tid);
  // R[tau] = Re(FFT(conj P))[tau] / N  / (H*E)
  const float scale = 1.0f / (4096.0f * 512.0f);
  for (int r = 0; r < LEN / TPB; ++r) {
    const int f = tid + r * TPB;
    R[f] = bufA[f].x * scale;
  }
  __syncthreads();

  for (int it = 0; it < KTOP; ++it) {
    float best = -INFINITY; int bi = 0;
    for (int r = 0; r < LEN / TPB; ++r) {
      const int f = tid + r * TPB;
      const float v = R[f];
      if (v > best) { best = v; bi = f; }
    }
    rv[tid] = best; ri[tid] = bi;
    __syncthreads();
    for (int off = TPB / 2; off > 0; off >>= 1) {
      if (tid < off && rv[tid + off] > rv[tid]) {
        rv[tid] = rv[tid + off]; ri[tid] = ri[tid + off];
      }
      __syncthreads();
    }
    if (tid == 0) {
      topv[it] = rv[0]; topi[it] = ri[0];
      R[ri[0]] = -INFINITY;                      // exclude for next pass
    }
    __syncthreads();
  }
  if (tid == 0) {
    const float m = topv[0];                     // descending order -> max
    float e[KTOP], den = 0.f;
    for (int i = 0; i < KTOP; ++i) { e[i] = expf(topv[i] - m); den += e[i]; }
    for (int i = 0; i < KTOP; ++i) {
      wout[b * KTOP + i] = e[i] / den;
      iout[b * KTOP + i] = topi[i];
    }
  }
}

__global__ __launch_bounds__(256) void k_gather(
    const float4* __restrict__ v, const float* __restrict__ wk,
    const int* __restrict__ ik, float4* __restrict__ out)
{
  __shared__ float sw[KTOP];
  __shared__ int   sidx[KTOP];
  const int b  = blockIdx.x >> 11;               // 2048 blocks per batch
  const int tp = blockIdx.x & 2047;
  if (threadIdx.x < KTOP) {
    sw[threadIdx.x]   = wk[b * KTOP + threadIdx.x];
    sidx[threadIdx.x] = ik[b * KTOP + threadIdx.x];
  }
  __syncthreads();
  const int t = tp * 2 + (threadIdx.x >> 7);     // 2 rows / block
  const int c = threadIdx.x & 127;               // float4 lane in 512-f row
  const size_t vbase = (size_t)b * LEN * 128;
  float4 acc = make_float4(0.f, 0.f, 0.f, 0.f);
  #pragma unroll
  for (int i = 0; i < KTOP; ++i) {
    const int st = (t + sidx[i]) & (LEN - 1);
    const float4 x = v[vbase + (size_t)st * 128 + c];
    acc.x += sw[i] * x.x; acc.y += sw[i] * x.y;
    acc.z += sw[i] * x.z; acc.w += sw[i] * x.w;
  }
  out[vbase + (size_t)t * 128 + c] = acc;
}

extern "C" void kernel_launch(void* const* d_in, const int* in_sizes, int n_in,
                              void* d_out, int out_size, void* d_ws, size_t ws_size,
                              hipStream_t stream) {
  const float* q = (const float*)d_in[0];
  const float* k = (const float*)d_in[1];
  const float* v = (const float*)d_in[2];
  float* out = (float*)d_out;

  float* Sf  = (float*)d_ws;                               // 262144 B
  float* wk  = (float*)((char*)d_ws + SF_BYTES);           // NB*KTOP f32
  int*   ik  = (int*)((char*)d_ws + SF_BYTES + NB * KTOP * sizeof(float));

  hipMemsetAsync(d_ws, 0, SF_BYTES, stream);
  k_fft_corr<<<NB * GPB, TPB, 0, stream>>>(q, k, Sf);
  k_ifft_topk<<<NB, TPB, 0, stream>>>(Sf, wk, ik);
  k_gather<<<NB * 2048, 256, 0, stream>>>((const float4*)v, wk, ik,
                                          (float4*)out);
}

// Round 2
// 413.170 us; speedup vs baseline: 2.0735x; 2.0735x over previous
//
#include <hip/hip_runtime.h>
#include <math.h>

// AutoCorrelation (Autoformer eval path), MI355X.
// B=8, L=4096, H=8, E=64 -> 512 channels; top_k = int(log(4096)) = 8.
// Pipeline (round 2: fix 16x overfetch via packed transpose through d_ws):
//   k_transpose: z[b][ch][t] = q[b][t][ch] + i*k[b][t][ch]   (LDS tile xpose)
//   k_fft_corr : per-channel 4096-pt FFT of z (coalesced loads), cross-
//                spectrum summed over channels into Sf[b][f] (atomic fp32)
//   k_ifft_topk: R = Re(FFT(conj(Sf)))/(L*CH); top-8 + softmax -> w,idx
//   k_gather   : out[b,t,:] = sum_i w_i * v[b,(t+idx_i)%L,:]  (float4)

namespace {
constexpr int LEN  = 4096;
constexpr int HALF = 2048;
constexpr int NCH  = 512;          // H*E
constexpr int NB   = 8;            // batch
constexpr int KTOP = 8;            // int(1.0 * log(4096))
constexpr int TPB  = 256;
constexpr int CPB  = 8;            // channels per block (kernel 1)
constexpr int GPB  = NCH / CPB;    // 64 groups per batch
constexpr size_t SF_BYTES = (size_t)NB * LEN * 2 * sizeof(float); // 262144
constexpr size_t WI_BYTES = (size_t)NB * KTOP * sizeof(float);    // 256
constexpr size_t ZT_OFF   = SF_BYTES + 2 * WI_BYTES;              // 262656
constexpr size_t ZT_BYTES = (size_t)NB * NCH * LEN * 2 * sizeof(float); // 134 MB
}

// ---------------------------------------------------------------------------
// Radix-2 Stockham DIF, N=4096, forward (e^{-i}), auto-sorting.
// Caller: bufA filled + __syncthreads() done. Result lands back in bufA
// (12 stages = even number of ping-pongs). tw[t] = exp(-2*pi*i*t/4096).
__device__ __forceinline__ void fft4096_fwd(float2* __restrict__ bufA,
                                            float2* __restrict__ bufB,
                                            const float2* __restrict__ tw,
                                            int tid)
{
  float2* src = bufA;
  float2* dst = bufB;
  #pragma unroll
  for (int st = 0; st < 12; ++st) {
    const int s = 1 << st;
    #pragma unroll
    for (int r = 0; r < HALF / TPB; ++r) {
      const int j = tid + r * TPB;
      const int q = j & (s - 1);         // j % s
      const int p = j >> st;             // j / s
      const float2 a = src[j];
      const float2 b = src[j + HALF];
      const float2 w = tw[j - q];        // tw[p*s]
      const float dx = a.x - b.x, dy = a.y - b.y;
      const int o0 = j + s * p;          // q + 2*s*p
      dst[o0]     = make_float2(a.x + b.x, a.y + b.y);
      dst[o0 + s] = make_float2(dx * w.x - dy * w.y, dx * w.y + dy * w.x);
    }
    __syncthreads();
    float2* t_ = src; src = dst; dst = t_;
  }
}

// ---------------------------------------------------------------------------
// Packed transpose: zt[b][c][t] = (q[b][t][c], k[b][t][c]).
// 64x64 tiles via LDS (pad 65 to dodge bank conflicts). Coalesced both sides:
// read 256B runs along channel dim, write 512B runs along time dim.
__global__ __launch_bounds__(TPB) void k_transpose(
    const float* __restrict__ qg, const float* __restrict__ kg,
    float2* __restrict__ zt)
{
  __shared__ float2 tile[64 * 65];
  const int bt  = blockIdx.x;               // [B][L/64][CH/64]
  const int b   = bt >> 9;                  // / (64*8)
  const int t0  = ((bt >> 3) & 63) * 64;
  const int c0  = (bt & 7) * 64;
  const int tid = threadIdx.x;
  const size_t base = (size_t)b * LEN * NCH;

  #pragma unroll
  for (int r = 0; r < 16; ++r) {
    const int idx  = r * TPB + tid;         // [0,4096)
    const int ch_l = idx & 63;
    const int t_l  = idx >> 6;
    const size_t g = base + (size_t)(t0 + t_l) * NCH + (c0 + ch_l);
    tile[t_l * 65 + ch_l] = make_float2(qg[g], kg[g]);
  }
  __syncthreads();
  #pragma unroll
  for (int r = 0; r < 16; ++r) {
    const int idx  = r * TPB + tid;
    const int t_l  = idx & 63;
    const int ch_l = idx >> 6;
    zt[((size_t)b * NCH + (c0 + ch_l)) * LEN + (t0 + t_l)] =
        tile[t_l * 65 + ch_l];
  }
}

// ---------------------------------------------------------------------------
// Coalesced-input FFT + cross-spectrum accumulate.
__global__ __launch_bounds__(TPB) void k_fft_corr(
    const float2* __restrict__ zt,          // [NB][NCH][LEN]
    float* __restrict__ Sf)                 // [NB][LEN][2]
{
  __shared__ float2 bufA[LEN];
  __shared__ float2 bufB[LEN];
  __shared__ float2 tw[HALF];
  const int tid = threadIdx.x;
  const int b   = blockIdx.x / GPB;
  const int g   = blockIdx.x % GPB;
  const int ch0 = g * CPB;

  for (int t = tid; t < HALF; t += TPB) {
    float s, c;
    __sincosf((float)t * (float)(-2.0 * M_PI / 4096.0), &s, &c);
    tw[t] = make_float2(c, s);
  }

  float2 acc[LEN / TPB];                    // 16 bins/thread, registers
  #pragma unroll
  for (int r = 0; r < LEN / TPB; ++r) acc[r] = make_float2(0.f, 0.f);

  for (int cc = 0; cc < CPB; ++cc) {
    const float2* src = zt + ((size_t)b * NCH + (ch0 + cc)) * LEN;
    __syncthreads();                        // prev P-read done; tw ready
    #pragma unroll
    for (int r = 0; r < LEN / TPB; ++r) {
      const int t = tid + r * TPB;
      bufA[t] = src[t];                     // z = q + i*k, coalesced
    }
    __syncthreads();
    fft4096_fwd(bufA, bufB, tw, tid);
    // P[f] = Qf*conj(Kf) = (i/4)*(A+B)*conj(A-B),
    // A = Z[f], B = conj(Z[(N-f)%N])
    #pragma unroll
    for (int r = 0; r < LEN / TPB; ++r) {
      const int f = tid + r * TPB;
      const float2 A  = bufA[f];
      float2 Bv = bufA[(LEN - f) & (LEN - 1)];
      Bv.y = -Bv.y;
      const float Sx = A.x + Bv.x, Sy = A.y + Bv.y;
      const float Dx = A.x - Bv.x, Dy = -(A.y - Bv.y); // conj(A-B)
      const float Mx = Sx * Dx - Sy * Dy;
      const float My = Sx * Dy + Sy * Dx;
      acc[r].x += -0.25f * My;              // *(i/4)
      acc[r].y +=  0.25f * Mx;
    }
  }
  float* dstp = Sf + (size_t)b * LEN * 2;
  #pragma unroll
  for (int r = 0; r < LEN / TPB; ++r) {
    const int f = tid + r * TPB;
    atomicAdd(&dstp[2 * f],     acc[r].x);
    atomicAdd(&dstp[2 * f + 1], acc[r].y);
  }
}

// Fallback (ws too small for transposed copy): round-1 strided-load version.
__global__ __launch_bounds__(TPB) void k_fft_corr_strided(
    const float* __restrict__ qg, const float* __restrict__ kg,
    float* __restrict__ Sf)
{
  __shared__ float2 bufA[LEN];
  __shared__ float2 bufB[LEN];
  __shared__ float2 tw[HALF];
  const int tid = threadIdx.x;
  const int b   = blockIdx.x / GPB;
  const int g   = blockIdx.x % GPB;
  const int ch0 = g * CPB;

  for (int t = tid; t < HALF; t += TPB) {
    float s, c;
    __sincosf((float)t * (float)(-2.0 * M_PI / 4096.0), &s, &c);
    tw[t] = make_float2(c, s);
  }
  float2 acc[LEN / TPB];
  #pragma unroll
  for (int r = 0; r < LEN / TPB; ++r) acc[r] = make_float2(0.f, 0.f);

  const size_t base = (size_t)b * LEN * NCH;
  for (int cc = 0; cc < CPB; ++cc) {
    const int ch = ch0 + cc;
    __syncthreads();
    #pragma unroll
    for (int r = 0; r < LEN / TPB; ++r) {
      const int t = tid + r * TPB;
      const size_t idx = base + (size_t)t * NCH + ch;
      bufA[t] = make_float2(qg[idx], kg[idx]);
    }
    __syncthreads();
    fft4096_fwd(bufA, bufB, tw, tid);
    #pragma unroll
    for (int r = 0; r < LEN / TPB; ++r) {
      const int f = tid + r * TPB;
      const float2 A  = bufA[f];
      float2 Bv = bufA[(LEN - f) & (LEN - 1)];
      Bv.y = -Bv.y;
      const float Sx = A.x + Bv.x, Sy = A.y + Bv.y;
      const float Dx = A.x - Bv.x, Dy = -(A.y - Bv.y);
      const float Mx = Sx * Dx - Sy * Dy;
      const float My = Sx * Dy + Sy * Dx;
      acc[r].x += -0.25f * My;
      acc[r].y +=  0.25f * Mx;
    }
  }
  float* dstp = Sf + (size_t)b * LEN * 2;
  #pragma unroll
  for (int r = 0; r < LEN / TPB; ++r) {
    const int f = tid + r * TPB;
    atomicAdd(&dstp[2 * f],     acc[r].x);
    atomicAdd(&dstp[2 * f + 1], acc[r].y);
  }
}

// ---------------------------------------------------------------------------
__global__ __launch_bounds__(TPB) void k_ifft_topk(
    const float* __restrict__ Sf,           // [NB][LEN][2]
    float* __restrict__ wout, int* __restrict__ iout)
{
  __shared__ float2 bufA[LEN];
  __shared__ float2 bufB[LEN];
  __shared__ float2 tw[HALF];
  __shared__ float  R[LEN];
  __shared__ float  rv[TPB];
  __shared__ int    ri[TPB];
  __shared__ float  topv[KTOP];
  __shared__ int    topi[KTOP];
  const int tid = threadIdx.x;
  const int b   = blockIdx.x;

  for (int t = tid; t < HALF; t += TPB) {
    float s, c;
    __sincosf((float)t * (float)(-2.0 * M_PI / 4096.0), &s, &c);
    tw[t] = make_float2(c, s);
  }
  const float* srcp = Sf + (size_t)b * LEN * 2;
  for (int r = 0; r < LEN / TPB; ++r) {
    const int f = tid + r * TPB;
    bufA[f] = make_float2(srcp[2 * f], -srcp[2 * f + 1]);  // conj(P)
  }
  __syncthreads();
  fft4096_fwd(bufA, bufB, tw, tid);
  // R[tau] = Re(FFT(conj P))[tau] / N / (H*E)
  const float scale = 1.0f / (4096.0f * 512.0f);
  for (int r = 0; r < LEN / TPB; ++r) {
    const int f = tid + r * TPB;
    R[f] = bufA[f].x * scale;
  }
  __syncthreads();

  for (int it = 0; it < KTOP; ++it) {
    float best = -INFINITY; int bi = 0;
    for (int r = 0; r < LEN / TPB; ++r) {
      const int f = tid + r * TPB;
      const float v = R[f];
      if (v > best) { best = v; bi = f; }
    }
    rv[tid] = best; ri[tid] = bi;
    __syncthreads();
    for (int off = TPB / 2; off > 0; off >>= 1) {
      if (tid < off && rv[tid + off] > rv[tid]) {
        rv[tid] = rv[tid + off]; ri[tid] = ri[tid + off];
      }
      __syncthreads();
    }
    if (tid == 0) {
      topv[it] = rv[0]; topi[it] = ri[0];
      R[ri[0]] = -INFINITY;                 // exclude for next pass
    }
    __syncthreads();
  }
  if (tid == 0) {
    const float m = topv[0];                // descending order -> max
    float e[KTOP], den = 0.f;
    for (int i = 0; i < KTOP; ++i) { e[i] = expf(topv[i] - m); den += e[i]; }
    for (int i = 0; i < KTOP; ++i) {
      wout[b * KTOP + i] = e[i] / den;
      iout[b * KTOP + i] = topi[i];
    }
  }
}

// ---------------------------------------------------------------------------
__global__ __launch_bounds__(256) void k_gather(
    const float4* __restrict__ v, const float* __restrict__ wk,
    const int* __restrict__ ik, float4* __restrict__ out)
{
  __shared__ float sw[KTOP];
  __shared__ int   sidx[KTOP];
  const int b  = blockIdx.x >> 11;          // 2048 blocks per batch
  const int tp = blockIdx.x & 2047;
  if (threadIdx.x < KTOP) {
    sw[threadIdx.x]   = wk[b * KTOP + threadIdx.x];
    sidx[threadIdx.x] = ik[b * KTOP + threadIdx.x];
  }
  __syncthreads();
  const int t = tp * 2 + (threadIdx.x >> 7); // 2 rows / block
  const int c = threadIdx.x & 127;           // float4 lane in 512-f row
  const size_t vbase = (size_t)b * LEN * 128;
  float4 acc = make_float4(0.f, 0.f, 0.f, 0.f);
  #pragma unroll
  for (int i = 0; i < KTOP; ++i) {
    const int st = (t + sidx[i]) & (LEN - 1);
    const float4 x = v[vbase + (size_t)st * 128 + c];
    acc.x += sw[i] * x.x; acc.y += sw[i] * x.y;
    acc.z += sw[i] * x.z; acc.w += sw[i] * x.w;
  }
  out[vbase + (size_t)t * 128 + c] = acc;
}

// ---------------------------------------------------------------------------
extern "C" void kernel_launch(void* const* d_in, const int* in_sizes, int n_in,
                              void* d_out, int out_size, void* d_ws, size_t ws_size,
                              hipStream_t stream) {
  const float* q = (const float*)d_in[0];
  const float* k = (const float*)d_in[1];
  const float* v = (const float*)d_in[2];
  float* out = (float*)d_out;

  float*  Sf = (float*)d_ws;                               // 262144 B
  float*  wk = (float*)((char*)d_ws + SF_BYTES);
  int*    ik = (int*)((char*)d_ws + SF_BYTES + WI_BYTES);
  float2* zt = (float2*)((char*)d_ws + ZT_OFF);            // 134 MB

  hipMemsetAsync(d_ws, 0, SF_BYTES, stream);
  if (ws_size >= ZT_OFF + ZT_BYTES) {
    k_transpose<<<NB * 64 * 8, TPB, 0, stream>>>(q, k, zt);
    k_fft_corr<<<NB * GPB, TPB, 0, stream>>>(zt, Sf);
  } else {
    k_fft_corr_strided<<<NB * GPB, TPB, 0, stream>>>(q, k, Sf);
  }
  k_ifft_topk<<<NB, TPB, 0, stream>>>(Sf, wk, ik);
  k_gather<<<NB * 2048, 256, 0, stream>>>((const float4*)v, wk, ik,
                                          (float4*)out);
}

// Round 3
// 403.401 us; speedup vs baseline: 2.1237x; 1.0242x over previous
//
#include <hip/hip_runtime.h>
#include <math.h>

// AutoCorrelation (Autoformer eval path), MI355X.
// B=8, L=4096, H=8, E=64 -> 512 channels; top_k = int(log(4096)) = 8.
// Round 3: radix-16 in-place Stockham FFT (3 stages, 1 padded LDS buffer,
//          twiddle-by-chain), shfl-based top-k.
//   k_transpose: z[b][ch][t] = q[b][t][ch] + i*k[b][t][ch]   (LDS tile xpose)
//   k_fft_corr : per-channel 4096-pt FFT of z, cross-spectrum summed over
//                channels into Sf[b][f] (atomic fp32, ws zeroed first)
//   k_ifft_topk: R = Re(FFT(conj(Sf)))/(L*CH); top-8 + softmax -> w,idx
//   k_gather   : out[b,t,:] = sum_i w_i * v[b,(t+idx_i)%L,:]  (float4)

namespace {
constexpr int LEN  = 4096;
constexpr int NCH  = 512;          // H*E
constexpr int NB   = 8;            // batch
constexpr int KTOP = 8;            // int(1.0 * log(4096))
constexpr int TPB  = 256;
constexpr int CPB  = 4;            // channels per block (kernel 1)
constexpr int GPB  = NCH / CPB;    // 128 groups per batch
constexpr size_t SF_BYTES = (size_t)NB * LEN * 2 * sizeof(float); // 262144
constexpr size_t WI_BYTES = (size_t)NB * KTOP * sizeof(float);    // 256
constexpr size_t ZT_OFF   = SF_BYTES + 2 * WI_BYTES;              // 262656
constexpr size_t ZT_BYTES = (size_t)NB * NCH * LEN * 2 * sizeof(float); // 134MB
constexpr int PADN = LEN + (LEN >> 4);  // 4352 float2 = 34816 B
}

#define PD(i) ((i) + ((i) >> 4))

__device__ __forceinline__ float2 cmul(float2 a, float2 b) {
  return make_float2(a.x * b.x - a.y * b.y, a.x * b.y + a.y * b.x);
}

// Forward 16-point DFT (natural order), 4x4 Cooley-Tukey, all in registers.
__device__ __forceinline__ void dft16(const float2* __restrict__ a,
                                      float2* __restrict__ b) {
  const float C1 = 0.92387953251128674f;   // cos(pi/8)
  const float S1 = 0.38268343236508978f;   // sin(pi/8)
  const float R2 = 0.70710678118654752f;   // sqrt(2)/2
  float2 c[4][4];
  #pragma unroll
  for (int r0 = 0; r0 < 4; ++r0) {
    const float2 x0 = a[r0], x1 = a[4 + r0], x2 = a[8 + r0], x3 = a[12 + r0];
    const float2 s02 = make_float2(x0.x + x2.x, x0.y + x2.y);
    const float2 d02 = make_float2(x0.x - x2.x, x0.y - x2.y);
    const float2 s13 = make_float2(x1.x + x3.x, x1.y + x3.y);
    const float2 d13 = make_float2(x1.x - x3.x, x1.y - x3.y);
    c[r0][0] = make_float2(s02.x + s13.x, s02.y + s13.y);
    c[r0][2] = make_float2(s02.x - s13.x, s02.y - s13.y);
    c[r0][1] = make_float2(d02.x + d13.y, d02.y - d13.x);   // d02 - i*d13
    c[r0][3] = make_float2(d02.x - d13.y, d02.y + d13.x);   // d02 + i*d13
  }
  #pragma unroll
  for (int k0 = 0; k0 < 4; ++k0) {
    float2 t0 = c[0][k0], t1 = c[1][k0], t2 = c[2][k0], t3 = c[3][k0];
    if (k0 == 1) {
      t1 = cmul(t1, make_float2(C1, -S1));
      t2 = cmul(t2, make_float2(R2, -R2));
      t3 = cmul(t3, make_float2(S1, -C1));
    } else if (k0 == 2) {
      t1 = cmul(t1, make_float2(R2, -R2));
      t2 = make_float2(t2.y, -t2.x);                        // * -i
      t3 = cmul(t3, make_float2(-R2, -R2));
    } else if (k0 == 3) {
      t1 = cmul(t1, make_float2(S1, -C1));
      t2 = cmul(t2, make_float2(-R2, -R2));
      t3 = cmul(t3, make_float2(-C1, S1));
    }
    const float2 s02 = make_float2(t0.x + t2.x, t0.y + t2.y);
    const float2 d02 = make_float2(t0.x - t2.x, t0.y - t2.y);
    const float2 s13 = make_float2(t1.x + t3.x, t1.y + t3.y);
    const float2 d13 = make_float2(t1.x - t3.x, t1.y - t3.y);
    b[k0]      = make_float2(s02.x + s13.x, s02.y + s13.y);
    b[k0 + 8]  = make_float2(s02.x - s13.x, s02.y - s13.y);
    b[k0 + 4]  = make_float2(d02.x + d13.y, d02.y - d13.x);
    b[k0 + 12] = make_float2(d02.x - d13.y, d02.y + d13.x);
  }
}

// In-place radix-16 Stockham DIF, N=4096 = 16^3, forward (e^{-i}), natural
// order out. buf is PD-padded (PADN float2). Caller: buf filled + synced.
// Per stage: all threads read 16 pts -> barrier -> all write (safe in-place).
__device__ __forceinline__ void fft4096_ip(float2* __restrict__ buf, int tid)
{
  float2 a[16], b[16];
  const float NEG2PI_N = -6.283185307179586f / 4096.0f;
  // ---- stage 0: s=1, q=0, p=tid ----
  {
    #pragma unroll
    for (int r = 0; r < 16; ++r) a[r] = buf[PD(tid + 256 * r)];
    dft16(a, b);
    float sn, cs;
    __sincosf((float)tid * NEG2PI_N, &sn, &cs);
    const float2 w1 = make_float2(cs, sn);
    __syncthreads();
    float2 w = make_float2(1.f, 0.f);
    #pragma unroll
    for (int k = 0; k < 16; ++k) {
      buf[PD(16 * tid + k)] = cmul(b[k], w);
      w = cmul(w, w1);
    }
  }
  __syncthreads();
  // ---- stage 1: s=16 ----
  {
    const int q = tid & 15, p = tid >> 4;
    #pragma unroll
    for (int r = 0; r < 16; ++r) a[r] = buf[PD(tid + 256 * r)];
    dft16(a, b);
    float sn, cs;
    __sincosf((float)(16 * p) * NEG2PI_N, &sn, &cs);
    const float2 w1 = make_float2(cs, sn);
    __syncthreads();
    float2 w = make_float2(1.f, 0.f);
    const int ob = q + 256 * p;
    #pragma unroll
    for (int k = 0; k < 16; ++k) {
      buf[PD(ob + 16 * k)] = cmul(b[k], w);
      w = cmul(w, w1);
    }
  }
  __syncthreads();
  // ---- stage 2: s=256, p=0 -> no twiddles ----
  {
    #pragma unroll
    for (int r = 0; r < 16; ++r) a[r] = buf[PD(tid + 256 * r)];
    dft16(a, b);
    __syncthreads();
    #pragma unroll
    for (int k = 0; k < 16; ++k) buf[PD(tid + 256 * k)] = b[k];
  }
  __syncthreads();
}

// ---------------------------------------------------------------------------
// Packed transpose: zt[b][c][t] = (q[b][t][c], k[b][t][c]).
__global__ __launch_bounds__(TPB) void k_transpose(
    const float* __restrict__ qg, const float* __restrict__ kg,
    float2* __restrict__ zt)
{
  __shared__ float2 tile[64 * 65];
  const int bt  = blockIdx.x;               // [B][L/64][CH/64]
  const int b   = bt >> 9;
  const int t0  = ((bt >> 3) & 63) * 64;
  const int c0  = (bt & 7) * 64;
  const int tid = threadIdx.x;
  const size_t base = (size_t)b * LEN * NCH;

  #pragma unroll
  for (int r = 0; r < 16; ++r) {
    const int idx  = r * TPB + tid;
    const int ch_l = idx & 63;
    const int t_l  = idx >> 6;
    const size_t g = base + (size_t)(t0 + t_l) * NCH + (c0 + ch_l);
    tile[t_l * 65 + ch_l] = make_float2(qg[g], kg[g]);
  }
  __syncthreads();
  #pragma unroll
  for (int r = 0; r < 16; ++r) {
    const int idx  = r * TPB + tid;
    const int t_l  = idx & 63;
    const int ch_l = idx >> 6;
    zt[((size_t)b * NCH + (c0 + ch_l)) * LEN + (t0 + t_l)] =
        tile[t_l * 65 + ch_l];
  }
}

// ---------------------------------------------------------------------------
// Spectrum accumulate shared by both fft_corr variants.
// P[f] = Qf*conj(Kf) = (i/4)*(A+B)*conj(A-B), A=Z[f], B=conj(Z[(N-f)%N]).
__device__ __forceinline__ void spec_acc(const float2* __restrict__ buf,
                                         int tid, float2* __restrict__ acc)
{
  #pragma unroll
  for (int r = 0; r < 16; ++r) {
    const int f = tid + 256 * r;
    const float2 A = buf[PD(f)];
    float2 Bv = buf[PD((LEN - f) & (LEN - 1))];
    Bv.y = -Bv.y;
    const float Sx = A.x + Bv.x, Sy = A.y + Bv.y;
    const float Dx = A.x - Bv.x, Dy = -(A.y - Bv.y);
    const float Mx = Sx * Dx - Sy * Dy;
    const float My = Sx * Dy + Sy * Dx;
    acc[r].x += -0.25f * My;
    acc[r].y +=  0.25f * Mx;
  }
}

__global__ __launch_bounds__(TPB) void k_fft_corr(
    const float2* __restrict__ zt,          // [NB][NCH][LEN]
    float* __restrict__ Sf)                 // [NB][LEN][2]
{
  __shared__ float2 buf[PADN];
  const int tid = threadIdx.x;
  const int b   = blockIdx.x / GPB;
  const int g   = blockIdx.x % GPB;
  const int ch0 = g * CPB;

  float2 acc[16];
  #pragma unroll
  for (int r = 0; r < 16; ++r) acc[r] = make_float2(0.f, 0.f);

  for (int cc = 0; cc < CPB; ++cc) {
    const float4* src =
        (const float4*)(zt + ((size_t)b * NCH + (ch0 + cc)) * LEN);
    #pragma unroll
    for (int r = 0; r < 8; ++r) {
      const float4 x = src[tid + 256 * r];
      const int t = 2 * (tid + 256 * r);
      buf[PD(t)]     = make_float2(x.x, x.y);
      buf[PD(t + 1)] = make_float2(x.z, x.w);
    }
    __syncthreads();
    fft4096_ip(buf, tid);
    spec_acc(buf, tid, acc);
    __syncthreads();                        // reads done before next load
  }
  float* dstp = Sf + (size_t)b * LEN * 2;
  #pragma unroll
  for (int r = 0; r < 16; ++r) {
    const int f = tid + 256 * r;
    atomicAdd(&dstp[2 * f],     acc[r].x);
    atomicAdd(&dstp[2 * f + 1], acc[r].y);
  }
}

// Fallback (ws too small for transposed copy): strided loads from q,k.
__global__ __launch_bounds__(TPB) void k_fft_corr_strided(
    const float* __restrict__ qg, const float* __restrict__ kg,
    float* __restrict__ Sf)
{
  __shared__ float2 buf[PADN];
  const int tid = threadIdx.x;
  const int b   = blockIdx.x / GPB;
  const int g   = blockIdx.x % GPB;
  const int ch0 = g * CPB;

  float2 acc[16];
  #pragma unroll
  for (int r = 0; r < 16; ++r) acc[r] = make_float2(0.f, 0.f);

  const size_t base = (size_t)b * LEN * NCH;
  for (int cc = 0; cc < CPB; ++cc) {
    const int ch = ch0 + cc;
    #pragma unroll
    for (int r = 0; r < 16; ++r) {
      const int t = tid + 256 * r;
      const size_t idx = base + (size_t)t * NCH + ch;
      buf[PD(t)] = make_float2(qg[idx], kg[idx]);
    }
    __syncthreads();
    fft4096_ip(buf, tid);
    spec_acc(buf, tid, acc);
    __syncthreads();
  }
  float* dstp = Sf + (size_t)b * LEN * 2;
  #pragma unroll
  for (int r = 0; r < 16; ++r) {
    const int f = tid + 256 * r;
    atomicAdd(&dstp[2 * f],     acc[r].x);
    atomicAdd(&dstp[2 * f + 1], acc[r].y);
  }
}

// ---------------------------------------------------------------------------
__global__ __launch_bounds__(TPB) void k_ifft_topk(
    const float* __restrict__ Sf,           // [NB][LEN][2]
    float* __restrict__ wout, int* __restrict__ iout)
{
  __shared__ float2 buf[PADN];
  __shared__ float swv[4];
  __shared__ int   swi[4];
  __shared__ int   gsel;
  __shared__ float topv[KTOP];
  __shared__ int   topi[KTOP];
  const int tid = threadIdx.x;
  const int b   = blockIdx.x;

  const float2* srcp = (const float2*)Sf + (size_t)b * LEN;
  #pragma unroll
  for (int r = 0; r < 16; ++r) {
    const int f = tid + 256 * r;
    const float2 s = srcp[f];
    buf[PD(f)] = make_float2(s.x, -s.y);    // conj(P)
  }
  __syncthreads();
  fft4096_ip(buf, tid);

  // R[tau] = Re(FFT(conj P))[tau] / N / (H*E), kept in registers
  const float scale = 1.0f / (4096.0f * 512.0f);
  float rv[16];
  #pragma unroll
  for (int r = 0; r < 16; ++r) rv[r] = buf[PD(tid + 256 * r)].x * scale;

  const int lane = tid & 63, wv = tid >> 6;
  for (int it = 0; it < KTOP; ++it) {
    float best = -INFINITY;
    int   bi   = 0x7fffffff;
    #pragma unroll
    for (int r = 0; r < 16; ++r) {
      if (rv[r] > best) { best = rv[r]; bi = tid + 256 * r; }
    }
    #pragma unroll
    for (int off = 32; off > 0; off >>= 1) {
      const float ov = __shfl_xor(best, off);
      const int   oi = __shfl_xor(bi, off);
      if (ov > best || (ov == best && oi < bi)) { best = ov; bi = oi; }
    }
    if (lane == 0) { swv[wv] = best; swi[wv] = bi; }
    __syncthreads();
    if (tid == 0) {
      float gv = swv[0]; int gi = swi[0];
      for (int w2 = 1; w2 < 4; ++w2)
        if (swv[w2] > gv || (swv[w2] == gv && swi[w2] < gi)) {
          gv = swv[w2]; gi = swi[w2];
        }
      topv[it] = gv; topi[it] = gi; gsel = gi;
    }
    __syncthreads();
    const int gi = gsel;
    if ((gi & 255) == tid) {
      const int rr = gi >> 8;
      #pragma unroll
      for (int r = 0; r < 16; ++r)          // static idx (avoid scratch)
        if (r == rr) rv[r] = -INFINITY;
    }
  }
  if (tid == 0) {
    const float m = topv[0];
    float e[KTOP], den = 0.f;
    #pragma unroll
    for (int i = 0; i < KTOP; ++i) { e[i] = expf(topv[i] - m); den += e[i]; }
    #pragma unroll
    for (int i = 0; i < KTOP; ++i) {
      wout[b * KTOP + i] = e[i] / den;
      iout[b * KTOP + i] = topi[i];
    }
  }
}

// ---------------------------------------------------------------------------
__global__ __launch_bounds__(256) void k_gather(
    const float4* __restrict__ v, const float* __restrict__ wk,
    const int* __restrict__ ik, float4* __restrict__ out)
{
  __shared__ float sw[KTOP];
  __shared__ int   sidx[KTOP];
  const int b  = blockIdx.x >> 11;          // 2048 blocks per batch
  const int tp = blockIdx.x & 2047;
  if (threadIdx.x < KTOP) {
    sw[threadIdx.x]   = wk[b * KTOP + threadIdx.x];
    sidx[threadIdx.x] = ik[b * KTOP + threadIdx.x];
  }
  __syncthreads();
  const int t = tp * 2 + (threadIdx.x >> 7); // 2 rows / block
  const int c = threadIdx.x & 127;           // float4 lane in 512-f row
  const size_t vbase = (size_t)b * LEN * 128;
  float4 acc = make_float4(0.f, 0.f, 0.f, 0.f);
  #pragma unroll
  for (int i = 0; i < KTOP; ++i) {
    const int st = (t + sidx[i]) & (LEN - 1);
    const float4 x = v[vbase + (size_t)st * 128 + c];
    acc.x += sw[i] * x.x; acc.y += sw[i] * x.y;
    acc.z += sw[i] * x.z; acc.w += sw[i] * x.w;
  }
  out[vbase + (size_t)t * 128 + c] = acc;
}

// ---------------------------------------------------------------------------
extern "C" void kernel_launch(void* const* d_in, const int* in_sizes, int n_in,
                              void* d_out, int out_size, void* d_ws, size_t ws_size,
                              hipStream_t stream) {
  const float* q = (const float*)d_in[0];
  const float* k = (const float*)d_in[1];
  const float* v = (const float*)d_in[2];

  float*  Sf = (float*)d_ws;                               // 262144 B
  float*  wk = (float*)((char*)d_ws + SF_BYTES);
  int*    ik = (int*)((char*)d_ws + SF_BYTES + WI_BYTES);
  float2* zt = (float2*)((char*)d_ws + ZT_OFF);            // 134 MB

  hipMemsetAsync(d_ws, 0, SF_BYTES, stream);
  if (ws_size >= ZT_OFF + ZT_BYTES) {
    k_transpose<<<NB * 64 * 8, TPB, 0, stream>>>(q, k, zt);
    k_fft_corr<<<NB * GPB, TPB, 0, stream>>>(zt, Sf);
  } else {
    k_fft_corr_strided<<<NB * GPB, TPB, 0, stream>>>(q, k, Sf);
  }
  k_ifft_topk<<<NB, TPB, 0, stream>>>(Sf, wk, ik);
  k_gather<<<NB * 2048, 256, 0, stream>>>((const float4*)v, wk, ik,
                                          (float4*)(float*)d_out);
}

// Round 7
// 362.061 us; speedup vs baseline: 2.3662x; 1.1142x over previous
//
#include <hip/hip_runtime.h>
#include <math.h>

// AutoCorrelation (Autoformer eval path), MI355X.
// B=8, L=4096, H=8, E=64 -> 512 channels; top_k = int(log(4096)) = 8.
// Round 4 (third resubmit; rounds 4-6 hit GPU-acquisition timeouts, no
// data): software-pipelined k_fft_corr — global_load_lds staging of the
// next channel into a linear LDS buffer, raw s_barrier + counted waitcnt so
// the prefetch stays in flight across the whole FFT.
//   k_transpose: z[b][ch][t] = q[b][t][ch] + i*k[b][t][ch]   (LDS tile xpose)
//   k_fft_corr : per-channel 4096-pt radix-16 FFT of z, cross-spectrum
//                summed over channels into Sf[b][f] (atomic fp32)
//   k_ifft_topk: R = Re(FFT(conj(Sf)))/(L*CH); top-8 + softmax -> w,idx
//   k_gather   : out[b,t,:] = sum_i w_i * v[b,(t+idx_i)%L,:]  (float4)

namespace {
constexpr int LEN  = 4096;
constexpr int NCH  = 512;          // H*E
constexpr int NB   = 8;            // batch
constexpr int KTOP = 8;            // int(1.0 * log(4096))
constexpr int TPB  = 256;
constexpr int CPB  = 8;            // channels per block (kernel 1)
constexpr int GPB  = NCH / CPB;    // 64 groups per batch -> 512 blocks
constexpr size_t SF_BYTES = (size_t)NB * LEN * 2 * sizeof(float); // 262144
constexpr size_t WI_BYTES = (size_t)NB * KTOP * sizeof(float);    // 256
constexpr size_t ZT_OFF   = SF_BYTES + 2 * WI_BYTES;              // 262656
constexpr size_t ZT_BYTES = (size_t)NB * NCH * LEN * 2 * sizeof(float); // 134MB
constexpr int PADN = LEN + (LEN >> 4);  // 4352 float2 = 34816 B
}

#define PD(i) ((i) + ((i) >> 4))

__device__ __forceinline__ float2 cmul(float2 a, float2 b) {
  return make_float2(a.x * b.x - a.y * b.y, a.x * b.y + a.y * b.x);
}

// async global->LDS, 16B per lane; LDS dest is wave-uniform base + lane*16.
__device__ __forceinline__ void gload_lds16(const void* g, void* l) {
  __builtin_amdgcn_global_load_lds(
      (const __attribute__((address_space(1))) void*)g,
      (__attribute__((address_space(3))) void*)l, 16, 0, 0);
}

#define LGKM_BAR()                                          \
  do {                                                      \
    asm volatile("s_waitcnt lgkmcnt(0)" ::: "memory");      \
    __builtin_amdgcn_s_barrier();                           \
  } while (0)
#define FULL_BAR()                                          \
  do {                                                      \
    asm volatile("s_waitcnt vmcnt(0) lgkmcnt(0)" ::: "memory"); \
    __builtin_amdgcn_s_barrier();                           \
  } while (0)

// Forward 16-point DFT (natural order), 4x4 Cooley-Tukey, all in registers.
__device__ __forceinline__ void dft16(const float2* __restrict__ a,
                                      float2* __restrict__ b) {
  const float C1 = 0.92387953251128674f;   // cos(pi/8)
  const float S1 = 0.38268343236508978f;   // sin(pi/8)
  const float R2 = 0.70710678118654752f;   // sqrt(2)/2
  float2 c[4][4];
  #pragma unroll
  for (int r0 = 0; r0 < 4; ++r0) {
    const float2 x0 = a[r0], x1 = a[4 + r0], x2 = a[8 + r0], x3 = a[12 + r0];
    const float2 s02 = make_float2(x0.x + x2.x, x0.y + x2.y);
    const float2 d02 = make_float2(x0.x - x2.x, x0.y - x2.y);
    const float2 s13 = make_float2(x1.x + x3.x, x1.y + x3.y);
    const float2 d13 = make_float2(x1.x - x3.x, x1.y - x3.y);
    c[r0][0] = make_float2(s02.x + s13.x, s02.y + s13.y);
    c[r0][2] = make_float2(s02.x - s13.x, s02.y - s13.y);
    c[r0][1] = make_float2(d02.x + d13.y, d02.y - d13.x);   // d02 - i*d13
    c[r0][3] = make_float2(d02.x - d13.y, d02.y + d13.x);   // d02 + i*d13
  }
  #pragma unroll
  for (int k0 = 0; k0 < 4; ++k0) {
    float2 t0 = c[0][k0], t1 = c[1][k0], t2 = c[2][k0], t3 = c[3][k0];
    if (k0 == 1) {
      t1 = cmul(t1, make_float2(C1, -S1));
      t2 = cmul(t2, make_float2(R2, -R2));
      t3 = cmul(t3, make_float2(S1, -C1));
    } else if (k0 == 2) {
      t1 = cmul(t1, make_float2(R2, -R2));
      t2 = make_float2(t2.y, -t2.x);                        // * -i
      t3 = cmul(t3, make_float2(-R2, -R2));
    } else if (k0 == 3) {
      t1 = cmul(t1, make_float2(S1, -C1));
      t2 = cmul(t2, make_float2(-R2, -R2));
      t3 = cmul(t3, make_float2(-C1, S1));
    }
    const float2 s02 = make_float2(t0.x + t2.x, t0.y + t2.y);
    const float2 d02 = make_float2(t0.x - t2.x, t0.y - t2.y);
    const float2 s13 = make_float2(t1.x + t3.x, t1.y + t3.y);
    const float2 d13 = make_float2(t1.x - t3.x, t1.y - t3.y);
    b[k0]      = make_float2(s02.x + s13.x, s02.y + s13.y);
    b[k0 + 8]  = make_float2(s02.x - s13.x, s02.y - s13.y);
    b[k0 + 4]  = make_float2(d02.x + d13.y, d02.y - d13.x);
    b[k0 + 12] = make_float2(d02.x - d13.y, d02.y + d13.x);
  }
}

// In-place radix-16 Stockham DIF, N=4096=16^3 (standard __syncthreads
// version; used by k_ifft_topk and the strided fallback).
__device__ __forceinline__ void fft4096_ip(float2* __restrict__ buf, int tid)
{
  float2 a[16], b[16];
  const float NEG2PI_N = -6.283185307179586f / 4096.0f;
  {
    #pragma unroll
    for (int r = 0; r < 16; ++r) a[r] = buf[PD(tid + 256 * r)];
    dft16(a, b);
    float sn, cs;
    __sincosf((float)tid * NEG2PI_N, &sn, &cs);
    const float2 w1 = make_float2(cs, sn);
    __syncthreads();
    float2 w = make_float2(1.f, 0.f);
    #pragma unroll
    for (int k = 0; k < 16; ++k) {
      buf[PD(16 * tid + k)] = cmul(b[k], w);
      w = cmul(w, w1);
    }
  }
  __syncthreads();
  {
    const int q = tid & 15, p = tid >> 4;
    #pragma unroll
    for (int r = 0; r < 16; ++r) a[r] = buf[PD(tid + 256 * r)];
    dft16(a, b);
    float sn, cs;
    __sincosf((float)(16 * p) * NEG2PI_N, &sn, &cs);
    const float2 w1 = make_float2(cs, sn);
    __syncthreads();
    float2 w = make_float2(1.f, 0.f);
    const int ob = q + 256 * p;
    #pragma unroll
    for (int k = 0; k < 16; ++k) {
      buf[PD(ob + 16 * k)] = cmul(b[k], w);
      w = cmul(w, w1);
    }
  }
  __syncthreads();
  {
    #pragma unroll
    for (int r = 0; r < 16; ++r) a[r] = buf[PD(tid + 256 * r)];
    dft16(a, b);
    __syncthreads();
    #pragma unroll
    for (int k = 0; k < 16; ++k) buf[PD(tid + 256 * k)] = b[k];
  }
  __syncthreads();
}

// ---------------------------------------------------------------------------
// Packed transpose: zt[b][c][t] = (q[b][t][c], k[b][t][c]).
__global__ __launch_bounds__(TPB) void k_transpose(
    const float* __restrict__ qg, const float* __restrict__ kg,
    float2* __restrict__ zt)
{
  __shared__ float2 tile[64 * 65];
  const int bt  = blockIdx.x;               // [B][L/64][CH/64]
  const int b   = bt >> 9;
  const int t0  = ((bt >> 3) & 63) * 64;
  const int c0  = (bt & 7) * 64;
  const int tid = threadIdx.x;
  const size_t base = (size_t)b * LEN * NCH;

  #pragma unroll
  for (int r = 0; r < 16; ++r) {
    const int idx  = r * TPB + tid;
    const int ch_l = idx & 63;
    const int t_l  = idx >> 6;
    const size_t g = base + (size_t)(t0 + t_l) * NCH + (c0 + ch_l);
    tile[t_l * 65 + ch_l] = make_float2(qg[g], kg[g]);
  }
  __syncthreads();
  #pragma unroll
  for (int r = 0; r < 16; ++r) {
    const int idx  = r * TPB + tid;
    const int t_l  = idx & 63;
    const int ch_l = idx >> 6;
    zt[((size_t)b * NCH + (c0 + ch_l)) * LEN + (t0 + t_l)] =
        tile[t_l * 65 + ch_l];
  }
}

// ---------------------------------------------------------------------------
// P[f] = Qf*conj(Kf) = (i/4)*(A+B)*conj(A-B), A=Z[f], B=conj(Z[(N-f)%N]).
__device__ __forceinline__ void spec_acc(const float2* __restrict__ buf,
                                         int tid, float2* __restrict__ acc)
{
  #pragma unroll
  for (int r = 0; r < 16; ++r) {
    const int f = tid + 256 * r;
    const float2 A = buf[PD(f)];
    float2 Bv = buf[PD((LEN - f) & (LEN - 1))];
    Bv.y = -Bv.y;
    const float Sx = A.x + Bv.x, Sy = A.y + Bv.y;
    const float Dx = A.x - Bv.x, Dy = -(A.y - Bv.y);
    const float Mx = Sx * Dx - Sy * Dy;
    const float My = Sx * Dy + Sy * Dx;
    acc[r].x += -0.25f * My;
    acc[r].y +=  0.25f * Mx;
  }
}

// Pipelined: bufS (linear) staged async while FFT runs on bufA (padded).
// Raw s_barrier + lgkmcnt-only drains keep the prefetch vmcnt outstanding
// across the FFT; vmcnt(0) drained once per channel (FULL_BAR) right before
// bufS is consumed again. bufS is untouched between issue and that barrier,
// so the relaxation is race-free by construction.
__global__ __launch_bounds__(TPB) void k_fft_corr(
    const float2* __restrict__ zt,          // [NB][NCH][LEN]
    float* __restrict__ Sf)                 // [NB][LEN][2]
{
  __shared__ float2 bufA[PADN];             // padded FFT workspace
  __shared__ float2 bufS[LEN];              // linear staging buffer
  const int tid  = threadIdx.x;
  const int lane = tid & 63;
  const int wv   = tid >> 6;
  const int b    = blockIdx.x / GPB;
  const int g    = blockIdx.x % GPB;
  const float2* base = zt + ((size_t)b * NCH + g * CPB) * LEN;

  float2 acc[16];
  #pragma unroll
  for (int r = 0; r < 16; ++r) acc[r] = make_float2(0.f, 0.f);

  // prologue: stage channel 0 (each wave copies its 8 KB quarter)
  {
    const char* gs = (const char*)base + (size_t)wv * 8192 + (size_t)lane * 16;
    char* ls = (char*)bufS + wv * 8192;
    #pragma unroll
    for (int i = 0; i < 8; ++i)
      gload_lds16(gs + i * 1024, ls + i * 1024);
  }
  FULL_BAR();

  const float NEG2PI_N = -6.283185307179586f / 4096.0f;
  for (int cc = 0; cc < CPB; ++cc) {
    float2 a[16], bb[16];
    float sn, cs;
    // ---- stage 0: read linear bufS (bank-clean: 2-way aliasing only) ----
    #pragma unroll
    for (int r = 0; r < 16; ++r) a[r] = bufS[tid + 256 * r];
    LGKM_BAR();                             // B1: bufS fully read by all
    if (cc + 1 < CPB) {                     // prefetch next channel (async)
      const char* gs = (const char*)(base + (size_t)(cc + 1) * LEN)
                       + (size_t)wv * 8192 + (size_t)lane * 16;
      char* ls = (char*)bufS + wv * 8192;
      #pragma unroll
      for (int i = 0; i < 8; ++i)
        gload_lds16(gs + i * 1024, ls + i * 1024);
    }
    dft16(a, bb);
    __sincosf((float)tid * NEG2PI_N, &sn, &cs);
    {
      const float2 w1 = make_float2(cs, sn);
      float2 w = make_float2(1.f, 0.f);
      #pragma unroll
      for (int k = 0; k < 16; ++k) {        // PD(16*tid+k) == 17*tid+k
        bufA[PD(16 * tid + k)] = cmul(bb[k], w);
        w = cmul(w, w1);
      }
    }
    LGKM_BAR();                             // B2
    // ---- stage 1 ----
    #pragma unroll
    for (int r = 0; r < 16; ++r) a[r] = bufA[PD(tid + 256 * r)];
    LGKM_BAR();                             // B3
    dft16(a, bb);
    {
      const int qq = tid & 15, p = tid >> 4;
      __sincosf((float)(16 * p) * NEG2PI_N, &sn, &cs);
      const float2 w1 = make_float2(cs, sn);
      float2 w = make_float2(1.f, 0.f);
      const int ob = qq + 256 * p;
      #pragma unroll
      for (int k = 0; k < 16; ++k) {
        bufA[PD(ob + 16 * k)] = cmul(bb[k], w);
        w = cmul(w, w1);
      }
    }
    LGKM_BAR();                             // B4
    // ---- stage 2 (p=0 -> no twiddles) ----
    #pragma unroll
    for (int r = 0; r < 16; ++r) a[r] = bufA[PD(tid + 256 * r)];
    LGKM_BAR();                             // B5
    dft16(a, bb);
    #pragma unroll
    for (int k = 0; k < 16; ++k) bufA[PD(tid + 256 * k)] = bb[k];
    LGKM_BAR();                             // B6
    spec_acc(bufA, tid, acc);
    FULL_BAR();                             // B7: spec reads + prefetch done
  }
  float* dstp = Sf + (size_t)b * LEN * 2;
  #pragma unroll
  for (int r = 0; r < 16; ++r) {
    const int f = tid + 256 * r;
    atomicAdd(&dstp[2 * f],     acc[r].x);
    atomicAdd(&dstp[2 * f + 1], acc[r].y);
  }
}

// Fallback (ws too small for transposed copy): strided loads from q,k.
__global__ __launch_bounds__(TPB) void k_fft_corr_strided(
    const float* __restrict__ qg, const float* __restrict__ kg,
    float* __restrict__ Sf)
{
  __shared__ float2 buf[PADN];
  const int tid = threadIdx.x;
  const int b   = blockIdx.x / GPB;
  const int g   = blockIdx.x % GPB;
  const int ch0 = g * CPB;

  float2 acc[16];
  #pragma unroll
  for (int r = 0; r < 16; ++r) acc[r] = make_float2(0.f, 0.f);

  const size_t base = (size_t)b * LEN * NCH;
  for (int cc = 0; cc < CPB; ++cc) {
    const int ch = ch0 + cc;
    #pragma unroll
    for (int r = 0; r < 16; ++r) {
      const int t = tid + 256 * r;
      const size_t idx = base + (size_t)t * NCH + ch;
      buf[PD(t)] = make_float2(qg[idx], kg[idx]);
    }
    __syncthreads();
    fft4096_ip(buf, tid);
    spec_acc(buf, tid, acc);
    __syncthreads();
  }
  float* dstp = Sf + (size_t)b * LEN * 2;
  #pragma unroll
  for (int r = 0; r < 16; ++r) {
    const int f = tid + 256 * r;
    atomicAdd(&dstp[2 * f],     acc[r].x);
    atomicAdd(&dstp[2 * f + 1], acc[r].y);
  }
}

// ---------------------------------------------------------------------------
__global__ __launch_bounds__(TPB) void k_ifft_topk(
    const float* __restrict__ Sf,           // [NB][LEN][2]
    float* __restrict__ wout, int* __restrict__ iout)
{
  __shared__ float2 buf[PADN];
  __shared__ float swv[4];
  __shared__ int   swi[4];
  __shared__ int   gsel;
  __shared__ float topv[KTOP];
  __shared__ int   topi[KTOP];
  const int tid = threadIdx.x;
  const int b   = blockIdx.x;

  const float2* srcp = (const float2*)Sf + (size_t)b * LEN;
  #pragma unroll
  for (int r = 0; r < 16; ++r) {
    const int f = tid + 256 * r;
    const float2 s = srcp[f];
    buf[PD(f)] = make_float2(s.x, -s.y);    // conj(P)
  }
  __syncthreads();
  fft4096_ip(buf, tid);

  const float scale = 1.0f / (4096.0f * 512.0f);
  float rv[16];
  #pragma unroll
  for (int r = 0; r < 16; ++r) rv[r] = buf[PD(tid + 256 * r)].x * scale;

  const int lane = tid & 63, wv = tid >> 6;
  for (int it = 0; it < KTOP; ++it) {
    float best = -INFINITY;
    int   bi   = 0x7fffffff;
    #pragma unroll
    for (int r = 0; r < 16; ++r) {
      if (rv[r] > best) { best = rv[r]; bi = tid + 256 * r; }
    }
    #pragma unroll
    for (int off = 32; off > 0; off >>= 1) {
      const float ov = __shfl_xor(best, off);
      const int   oi = __shfl_xor(bi, off);
      if (ov > best || (ov == best && oi < bi)) { best = ov; bi = oi; }
    }
    if (lane == 0) { swv[wv] = best; swi[wv] = bi; }
    __syncthreads();
    if (tid == 0) {
      float gv = swv[0]; int gi = swi[0];
      for (int w2 = 1; w2 < 4; ++w2)
        if (swv[w2] > gv || (swv[w2] == gv && swi[w2] < gi)) {
          gv = swv[w2]; gi = swi[w2];
        }
      topv[it] = gv; topi[it] = gi; gsel = gi;
    }
    __syncthreads();
    const int gi = gsel;
    if ((gi & 255) == tid) {
      const int rr = gi >> 8;
      #pragma unroll
      for (int r = 0; r < 16; ++r)          // static idx (avoid scratch)
        if (r == rr) rv[r] = -INFINITY;
    }
  }
  if (tid == 0) {
    const float m = topv[0];
    float e[KTOP], den = 0.f;
    #pragma unroll
    for (int i = 0; i < KTOP; ++i) { e[i] = expf(topv[i] - m); den += e[i]; }
    #pragma unroll
    for (int i = 0; i < KTOP; ++i) {
      wout[b * KTOP + i] = e[i] / den;
      iout[b * KTOP + i] = topi[i];
    }
  }
}

// ---------------------------------------------------------------------------
__global__ __launch_bounds__(256) void k_gather(
    const float4* __restrict__ v, const float* __restrict__ wk,
    const int* __restrict__ ik, float4* __restrict__ out)
{
  __shared__ float sw[KTOP];
  __shared__ int   sidx[KTOP];
  const int b  = blockIdx.x >> 11;          // 2048 blocks per batch
  const int tp = blockIdx.x & 2047;
  if (threadIdx.x < KTOP) {
    sw[threadIdx.x]   = wk[b * KTOP + threadIdx.x];
    sidx[threadIdx.x] = ik[b * KTOP + threadIdx.x];
  }
  __syncthreads();
  const int t = tp * 2 + (threadIdx.x >> 7); // 2 rows / block
  const int c = threadIdx.x & 127;           // float4 lane in 512-f row
  const size_t vbase = (size_t)b * LEN * 128;
  float4 acc = make_float4(0.f, 0.f, 0.f, 0.f);
  #pragma unroll
  for (int i = 0; i < KTOP; ++i) {
    const int st = (t + sidx[i]) & (LEN - 1);
    const float4 x = v[vbase + (size_t)st * 128 + c];
    acc.x += sw[i] * x.x; acc.y += sw[i] * x.y;
    acc.z += sw[i] * x.z; acc.w += sw[i] * x.w;
  }
  out[vbase + (size_t)t * 128 + c] = acc;
}

// ---------------------------------------------------------------------------
extern "C" void kernel_launch(void* const* d_in, const int* in_sizes, int n_in,
                              void* d_out, int out_size, void* d_ws, size_t ws_size,
                              hipStream_t stream) {
  const float* q = (const float*)d_in[0];
  const float* k = (const float*)d_in[1];
  const float* v = (const float*)d_in[2];

  float*  Sf = (float*)d_ws;                               // 262144 B
  float*  wk = (float*)((char*)d_ws + SF_BYTES);
  int*    ik = (int*)((char*)d_ws + SF_BYTES + WI_BYTES);
  float2* zt = (float2*)((char*)d_ws + ZT_OFF);            // 134 MB

  hipMemsetAsync(d_ws, 0, SF_BYTES, stream);
  if (ws_size >= ZT_OFF + ZT_BYTES) {
    k_transpose<<<NB * 64 * 8, TPB, 0, stream>>>(q, k, zt);
    k_fft_corr<<<NB * GPB, TPB, 0, stream>>>(zt, Sf);
  } else {
    k_fft_corr_strided<<<NB * GPB, TPB, 0, stream>>>(q, k, Sf);
  }
  k_ifft_topk<<<NB, TPB, 0, stream>>>(Sf, wk, ik);
  k_gather<<<NB * 2048, 256, 0, stream>>>((const float4*)v, wk, ik,
                                          (float4*)d_out);
}

// Round 8
// 359.198 us; speedup vs baseline: 2.3851x; 1.0080x over previous
//
#include <hip/hip_runtime.h>
#include <math.h>

// AutoCorrelation (Autoformer eval path), MI355X.
// B=8, L=4096, H=8, E=64 -> 512 channels; top_k = int(log(4096)) = 8.
// Round 8: (a) k_fft_corr hoists channel-invariant twiddle tables into
// registers (kills 2 sincos + 30 serial cmuls per channel); (b) k_gather
// XCD-batch swizzle (batch b -> XCD b) so each XCD L2 serves one v slab.
//   k_transpose: z[b][ch][t] = q[b][t][ch] + i*k[b][t][ch]   (LDS tile xpose)
//   k_fft_corr : per-channel 4096-pt radix-16 FFT of z, cross-spectrum
//                summed over channels into Sf[b][f] (atomic fp32)
//   k_ifft_topk: R = Re(FFT(conj(Sf)))/(L*CH); top-8 + softmax -> w,idx
//   k_gather   : out[b,t,:] = sum_i w_i * v[b,(t+idx_i)%L,:]  (float4)

namespace {
constexpr int LEN  = 4096;
constexpr int NCH  = 512;          // H*E
constexpr int NB   = 8;            // batch
constexpr int KTOP = 8;            // int(1.0 * log(4096))
constexpr int TPB  = 256;
constexpr int CPB  = 8;            // channels per block (kernel 1)
constexpr int GPB  = NCH / CPB;    // 64 groups per batch -> 512 blocks
constexpr size_t SF_BYTES = (size_t)NB * LEN * 2 * sizeof(float); // 262144
constexpr size_t WI_BYTES = (size_t)NB * KTOP * sizeof(float);    // 256
constexpr size_t ZT_OFF   = SF_BYTES + 2 * WI_BYTES;              // 262656
constexpr size_t ZT_BYTES = (size_t)NB * NCH * LEN * 2 * sizeof(float); // 134MB
constexpr int PADN = LEN + (LEN >> 4);  // 4352 float2 = 34816 B
}

#define PD(i) ((i) + ((i) >> 4))

__device__ __forceinline__ float2 cmul(float2 a, float2 b) {
  return make_float2(a.x * b.x - a.y * b.y, a.x * b.y + a.y * b.x);
}

// async global->LDS, 16B per lane; LDS dest is wave-uniform base + lane*16.
__device__ __forceinline__ void gload_lds16(const void* g, void* l) {
  __builtin_amdgcn_global_load_lds(
      (const __attribute__((address_space(1))) void*)g,
      (__attribute__((address_space(3))) void*)l, 16, 0, 0);
}

#define LGKM_BAR()                                          \
  do {                                                      \
    asm volatile("s_waitcnt lgkmcnt(0)" ::: "memory");      \
    __builtin_amdgcn_s_barrier();                           \
  } while (0)
#define FULL_BAR()                                          \
  do {                                                      \
    asm volatile("s_waitcnt vmcnt(0) lgkmcnt(0)" ::: "memory"); \
    __builtin_amdgcn_s_barrier();                           \
  } while (0)

// Forward 16-point DFT (natural order), 4x4 Cooley-Tukey, all in registers.
__device__ __forceinline__ void dft16(const float2* __restrict__ a,
                                      float2* __restrict__ b) {
  const float C1 = 0.92387953251128674f;   // cos(pi/8)
  const float S1 = 0.38268343236508978f;   // sin(pi/8)
  const float R2 = 0.70710678118654752f;   // sqrt(2)/2
  float2 c[4][4];
  #pragma unroll
  for (int r0 = 0; r0 < 4; ++r0) {
    const float2 x0 = a[r0], x1 = a[4 + r0], x2 = a[8 + r0], x3 = a[12 + r0];
    const float2 s02 = make_float2(x0.x + x2.x, x0.y + x2.y);
    const float2 d02 = make_float2(x0.x - x2.x, x0.y - x2.y);
    const float2 s13 = make_float2(x1.x + x3.x, x1.y + x3.y);
    const float2 d13 = make_float2(x1.x - x3.x, x1.y - x3.y);
    c[r0][0] = make_float2(s02.x + s13.x, s02.y + s13.y);
    c[r0][2] = make_float2(s02.x - s13.x, s02.y - s13.y);
    c[r0][1] = make_float2(d02.x + d13.y, d02.y - d13.x);   // d02 - i*d13
    c[r0][3] = make_float2(d02.x - d13.y, d02.y + d13.x);   // d02 + i*d13
  }
  #pragma unroll
  for (int k0 = 0; k0 < 4; ++k0) {
    float2 t0 = c[0][k0], t1 = c[1][k0], t2 = c[2][k0], t3 = c[3][k0];
    if (k0 == 1) {
      t1 = cmul(t1, make_float2(C1, -S1));
      t2 = cmul(t2, make_float2(R2, -R2));
      t3 = cmul(t3, make_float2(S1, -C1));
    } else if (k0 == 2) {
      t1 = cmul(t1, make_float2(R2, -R2));
      t2 = make_float2(t2.y, -t2.x);                        // * -i
      t3 = cmul(t3, make_float2(-R2, -R2));
    } else if (k0 == 3) {
      t1 = cmul(t1, make_float2(S1, -C1));
      t2 = cmul(t2, make_float2(-R2, -R2));
      t3 = cmul(t3, make_float2(-C1, S1));
    }
    const float2 s02 = make_float2(t0.x + t2.x, t0.y + t2.y);
    const float2 d02 = make_float2(t0.x - t2.x, t0.y - t2.y);
    const float2 s13 = make_float2(t1.x + t3.x, t1.y + t3.y);
    const float2 d13 = make_float2(t1.x - t3.x, t1.y - t3.y);
    b[k0]      = make_float2(s02.x + s13.x, s02.y + s13.y);
    b[k0 + 8]  = make_float2(s02.x - s13.x, s02.y - s13.y);
    b[k0 + 4]  = make_float2(d02.x + d13.y, d02.y - d13.x);
    b[k0 + 12] = make_float2(d02.x - d13.y, d02.y + d13.x);
  }
}

// In-place radix-16 Stockham DIF, N=4096=16^3 (standard __syncthreads
// version; used by k_ifft_topk and the strided fallback).
__device__ __forceinline__ void fft4096_ip(float2* __restrict__ buf, int tid)
{
  float2 a[16], b[16];
  const float NEG2PI_N = -6.283185307179586f / 4096.0f;
  {
    #pragma unroll
    for (int r = 0; r < 16; ++r) a[r] = buf[PD(tid + 256 * r)];
    dft16(a, b);
    float sn, cs;
    __sincosf((float)tid * NEG2PI_N, &sn, &cs);
    const float2 w1 = make_float2(cs, sn);
    __syncthreads();
    float2 w = make_float2(1.f, 0.f);
    #pragma unroll
    for (int k = 0; k < 16; ++k) {
      buf[PD(16 * tid + k)] = cmul(b[k], w);
      w = cmul(w, w1);
    }
  }
  __syncthreads();
  {
    const int q = tid & 15, p = tid >> 4;
    #pragma unroll
    for (int r = 0; r < 16; ++r) a[r] = buf[PD(tid + 256 * r)];
    dft16(a, b);
    float sn, cs;
    __sincosf((float)(16 * p) * NEG2PI_N, &sn, &cs);
    const float2 w1 = make_float2(cs, sn);
    __syncthreads();
    float2 w = make_float2(1.f, 0.f);
    const int ob = q + 256 * p;
    #pragma unroll
    for (int k = 0; k < 16; ++k) {
      buf[PD(ob + 16 * k)] = cmul(b[k], w);
      w = cmul(w, w1);
    }
  }
  __syncthreads();
  {
    #pragma unroll
    for (int r = 0; r < 16; ++r) a[r] = buf[PD(tid + 256 * r)];
    dft16(a, b);
    __syncthreads();
    #pragma unroll
    for (int k = 0; k < 16; ++k) buf[PD(tid + 256 * k)] = b[k];
  }
  __syncthreads();
}

// ---------------------------------------------------------------------------
// Packed transpose: zt[b][c][t] = (q[b][t][c], k[b][t][c]).
__global__ __launch_bounds__(TPB) void k_transpose(
    const float* __restrict__ qg, const float* __restrict__ kg,
    float2* __restrict__ zt)
{
  __shared__ float2 tile[64 * 65];
  const int bt  = blockIdx.x;               // [B][L/64][CH/64]
  const int b   = bt >> 9;
  const int t0  = ((bt >> 3) & 63) * 64;
  const int c0  = (bt & 7) * 64;
  const int tid = threadIdx.x;
  const size_t base = (size_t)b * LEN * NCH;

  #pragma unroll
  for (int r = 0; r < 16; ++r) {
    const int idx  = r * TPB + tid;
    const int ch_l = idx & 63;
    const int t_l  = idx >> 6;
    const size_t g = base + (size_t)(t0 + t_l) * NCH + (c0 + ch_l);
    tile[t_l * 65 + ch_l] = make_float2(qg[g], kg[g]);
  }
  __syncthreads();
  #pragma unroll
  for (int r = 0; r < 16; ++r) {
    const int idx  = r * TPB + tid;
    const int t_l  = idx & 63;
    const int ch_l = idx >> 6;
    zt[((size_t)b * NCH + (c0 + ch_l)) * LEN + (t0 + t_l)] =
        tile[t_l * 65 + ch_l];
  }
}

// ---------------------------------------------------------------------------
// P[f] = Qf*conj(Kf) = (i/4)*(A+B)*conj(A-B), A=Z[f], B=conj(Z[(N-f)%N]).
__device__ __forceinline__ void spec_acc(const float2* __restrict__ buf,
                                         int tid, float2* __restrict__ acc)
{
  #pragma unroll
  for (int r = 0; r < 16; ++r) {
    const int f = tid + 256 * r;
    const float2 A = buf[PD(f)];
    float2 Bv = buf[PD((LEN - f) & (LEN - 1))];
    Bv.y = -Bv.y;
    const float Sx = A.x + Bv.x, Sy = A.y + Bv.y;
    const float Dx = A.x - Bv.x, Dy = -(A.y - Bv.y);
    const float Mx = Sx * Dx - Sy * Dy;
    const float My = Sx * Dy + Sy * Dx;
    acc[r].x += -0.25f * My;
    acc[r].y +=  0.25f * Mx;
  }
}

// Pipelined: bufS (linear) staged async while FFT runs on bufA (padded).
// Twiddle tables tw0/tw1 are channel-invariant per thread -> hoisted into
// registers before the channel loop (identical chain => identical numerics).
__global__ __launch_bounds__(TPB) void k_fft_corr(
    const float2* __restrict__ zt,          // [NB][NCH][LEN]
    float* __restrict__ Sf)                 // [NB][LEN][2]
{
  __shared__ float2 bufA[PADN];             // padded FFT workspace
  __shared__ float2 bufS[LEN];              // linear staging buffer
  const int tid  = threadIdx.x;
  const int lane = tid & 63;
  const int wv   = tid >> 6;
  const int b    = blockIdx.x / GPB;
  const int g    = blockIdx.x % GPB;
  const float2* base = zt + ((size_t)b * NCH + g * CPB) * LEN;

  float2 acc[16];
  #pragma unroll
  for (int r = 0; r < 16; ++r) acc[r] = make_float2(0.f, 0.f);

  // hoisted twiddles: tw0[k] = W^(tid*k), tw1[k] = W^(16*(tid>>4)*k)
  const float NEG2PI_N = -6.283185307179586f / 4096.0f;
  float2 tw0[16], tw1[16];
  {
    float sn, cs;
    __sincosf((float)tid * NEG2PI_N, &sn, &cs);
    const float2 w1 = make_float2(cs, sn);
    tw0[0] = make_float2(1.f, 0.f);
    #pragma unroll
    for (int k = 1; k < 16; ++k) tw0[k] = cmul(tw0[k - 1], w1);
    __sincosf((float)(16 * (tid >> 4)) * NEG2PI_N, &sn, &cs);
    const float2 w1b = make_float2(cs, sn);
    tw1[0] = make_float2(1.f, 0.f);
    #pragma unroll
    for (int k = 1; k < 16; ++k) tw1[k] = cmul(tw1[k - 1], w1b);
  }

  // prologue: stage channel 0 (each wave copies its 8 KB quarter)
  {
    const char* gs = (const char*)base + (size_t)wv * 8192 + (size_t)lane * 16;
    char* ls = (char*)bufS + wv * 8192;
    #pragma unroll
    for (int i = 0; i < 8; ++i)
      gload_lds16(gs + i * 1024, ls + i * 1024);
  }
  FULL_BAR();

  for (int cc = 0; cc < CPB; ++cc) {
    float2 a[16], bb[16];
    // ---- stage 0: read linear bufS (bank-clean: 2-way aliasing only) ----
    #pragma unroll
    for (int r = 0; r < 16; ++r) a[r] = bufS[tid + 256 * r];
    LGKM_BAR();                             // B1: bufS fully read by all
    if (cc + 1 < CPB) {                     // prefetch next channel (async)
      const char* gs = (const char*)(base + (size_t)(cc + 1) * LEN)
                       + (size_t)wv * 8192 + (size_t)lane * 16;
      char* ls = (char*)bufS + wv * 8192;
      #pragma unroll
      for (int i = 0; i < 8; ++i)
        gload_lds16(gs + i * 1024, ls + i * 1024);
    }
    dft16(a, bb);
    #pragma unroll
    for (int k = 0; k < 16; ++k)            // PD(16*tid+k) == 17*tid+k
      bufA[PD(16 * tid + k)] = cmul(bb[k], tw0[k]);
    LGKM_BAR();                             // B2
    // ---- stage 1 ----
    #pragma unroll
    for (int r = 0; r < 16; ++r) a[r] = bufA[PD(tid + 256 * r)];
    LGKM_BAR();                             // B3
    dft16(a, bb);
    {
      const int ob = (tid & 15) + 256 * (tid >> 4);
      #pragma unroll
      for (int k = 0; k < 16; ++k)
        bufA[PD(ob + 16 * k)] = cmul(bb[k], tw1[k]);
    }
    LGKM_BAR();                             // B4
    // ---- stage 2 (p=0 -> no twiddles) ----
    #pragma unroll
    for (int r = 0; r < 16; ++r) a[r] = bufA[PD(tid + 256 * r)];
    LGKM_BAR();                             // B5
    dft16(a, bb);
    #pragma unroll
    for (int k = 0; k < 16; ++k) bufA[PD(tid + 256 * k)] = bb[k];
    LGKM_BAR();                             // B6
    spec_acc(bufA, tid, acc);
    FULL_BAR();                             // B7: spec reads + prefetch done
  }
  float* dstp = Sf + (size_t)b * LEN * 2;
  #pragma unroll
  for (int r = 0; r < 16; ++r) {
    const int f = tid + 256 * r;
    atomicAdd(&dstp[2 * f],     acc[r].x);
    atomicAdd(&dstp[2 * f + 1], acc[r].y);
  }
}

// Fallback (ws too small for transposed copy): strided loads from q,k.
__global__ __launch_bounds__(TPB) void k_fft_corr_strided(
    const float* __restrict__ qg, const float* __restrict__ kg,
    float* __restrict__ Sf)
{
  __shared__ float2 buf[PADN];
  const int tid = threadIdx.x;
  const int b   = blockIdx.x / GPB;
  const int g   = blockIdx.x % GPB;
  const int ch0 = g * CPB;

  float2 acc[16];
  #pragma unroll
  for (int r = 0; r < 16; ++r) acc[r] = make_float2(0.f, 0.f);

  const size_t base = (size_t)b * LEN * NCH;
  for (int cc = 0; cc < CPB; ++cc) {
    const int ch = ch0 + cc;
    #pragma unroll
    for (int r = 0; r < 16; ++r) {
      const int t = tid + 256 * r;
      const size_t idx = base + (size_t)t * NCH + ch;
      buf[PD(t)] = make_float2(qg[idx], kg[idx]);
    }
    __syncthreads();
    fft4096_ip(buf, tid);
    spec_acc(buf, tid, acc);
    __syncthreads();
  }
  float* dstp = Sf + (size_t)b * LEN * 2;
  #pragma unroll
  for (int r = 0; r < 16; ++r) {
    const int f = tid + 256 * r;
    atomicAdd(&dstp[2 * f],     acc[r].x);
    atomicAdd(&dstp[2 * f + 1], acc[r].y);
  }
}

// ---------------------------------------------------------------------------
__global__ __launch_bounds__(TPB) void k_ifft_topk(
    const float* __restrict__ Sf,           // [NB][LEN][2]
    float* __restrict__ wout, int* __restrict__ iout)
{
  __shared__ float2 buf[PADN];
  __shared__ float swv[4];
  __shared__ int   swi[4];
  __shared__ int   gsel;
  __shared__ float topv[KTOP];
  __shared__ int   topi[KTOP];
  const int tid = threadIdx.x;
  const int b   = blockIdx.x;

  const float2* srcp = (const float2*)Sf + (size_t)b * LEN;
  #pragma unroll
  for (int r = 0; r < 16; ++r) {
    const int f = tid + 256 * r;
    const float2 s = srcp[f];
    buf[PD(f)] = make_float2(s.x, -s.y);    // conj(P)
  }
  __syncthreads();
  fft4096_ip(buf, tid);

  const float scale = 1.0f / (4096.0f * 512.0f);
  float rv[16];
  #pragma unroll
  for (int r = 0; r < 16; ++r) rv[r] = buf[PD(tid + 256 * r)].x * scale;

  const int lane = tid & 63, wv = tid >> 6;
  for (int it = 0; it < KTOP; ++it) {
    float best = -INFINITY;
    int   bi   = 0x7fffffff;
    #pragma unroll
    for (int r = 0; r < 16; ++r) {
      if (rv[r] > best) { best = rv[r]; bi = tid + 256 * r; }
    }
    #pragma unroll
    for (int off = 32; off > 0; off >>= 1) {
      const float ov = __shfl_xor(best, off);
      const int   oi = __shfl_xor(bi, off);
      if (ov > best || (ov == best && oi < bi)) { best = ov; bi = oi; }
    }
    if (lane == 0) { swv[wv] = best; swi[wv] = bi; }
    __syncthreads();
    if (tid == 0) {
      float gv = swv[0]; int gi = swi[0];
      for (int w2 = 1; w2 < 4; ++w2)
        if (swv[w2] > gv || (swv[w2] == gv && swi[w2] < gi)) {
          gv = swv[w2]; gi = swi[w2];
        }
      topv[it] = gv; topi[it] = gi; gsel = gi;
    }
    __syncthreads();
    const int gi = gsel;
    if ((gi & 255) == tid) {
      const int rr = gi >> 8;
      #pragma unroll
      for (int r = 0; r < 16; ++r)          // static idx (avoid scratch)
        if (r == rr) rv[r] = -INFINITY;
    }
  }
  if (tid == 0) {
    const float m = topv[0];
    float e[KTOP], den = 0.f;
    #pragma unroll
    for (int i = 0; i < KTOP; ++i) { e[i] = expf(topv[i] - m); den += e[i]; }
    #pragma unroll
    for (int i = 0; i < KTOP; ++i) {
      wout[b * KTOP + i] = e[i] / den;
      iout[b * KTOP + i] = topi[i];
    }
  }
}

// ---------------------------------------------------------------------------
// XCD-batch swizzle: blockIdx % 8 selects the XCD (round-robin dispatch), so
// mapping batch = blockIdx & 7 pins each batch's v-slab (8.4 MB) to one
// XCD's L2 instead of streaming all 8 slabs through every L2.
__global__ __launch_bounds__(256) void k_gather(
    const float4* __restrict__ v, const float* __restrict__ wk,
    const int* __restrict__ ik, float4* __restrict__ out)
{
  __shared__ float sw[KTOP];
  __shared__ int   sidx[KTOP];
  const int b  = blockIdx.x & 7;            // batch == XCD
  const int tp = blockIdx.x >> 3;           // [0,2048)
  if (threadIdx.x < KTOP) {
    sw[threadIdx.x]   = wk[b * KTOP + threadIdx.x];
    sidx[threadIdx.x] = ik[b * KTOP + threadIdx.x];
  }
  __syncthreads();
  const int t = tp * 2 + (threadIdx.x >> 7); // 2 rows / block
  const int c = threadIdx.x & 127;           // float4 lane in 512-f row
  const size_t vbase = (size_t)b * LEN * 128;
  float4 acc = make_float4(0.f, 0.f, 0.f, 0.f);
  #pragma unroll
  for (int i = 0; i < KTOP; ++i) {
    const int st = (t + sidx[i]) & (LEN - 1);
    const float4 x = v[vbase + (size_t)st * 128 + c];
    acc.x += sw[i] * x.x; acc.y += sw[i] * x.y;
    acc.z += sw[i] * x.z; acc.w += sw[i] * x.w;
  }
  out[vbase + (size_t)t * 128 + c] = acc;
}

// ---------------------------------------------------------------------------
extern "C" void kernel_launch(void* const* d_in, const int* in_sizes, int n_in,
                              void* d_out, int out_size, void* d_ws, size_t ws_size,
                              hipStream_t stream) {
  const float* q = (const float*)d_in[0];
  const float* k = (const float*)d_in[1];
  const float* v = (const float*)d_in[2];

  float*  Sf = (float*)d_ws;                               // 262144 B
  float*  wk = (float*)((char*)d_ws + SF_BYTES);
  int*    ik = (int*)((char*)d_ws + SF_BYTES + WI_BYTES);
  float2* zt = (float2*)((char*)d_ws + ZT_OFF);            // 134 MB

  hipMemsetAsync(d_ws, 0, SF_BYTES, stream);
  if (ws_size >= ZT_OFF + ZT_BYTES) {
    k_transpose<<<NB * 64 * 8, TPB, 0, stream>>>(q, k, zt);
    k_fft_corr<<<NB * GPB, TPB, 0, stream>>>(zt, Sf);
  } else {
    k_fft_corr_strided<<<NB * GPB, TPB, 0, stream>>>(q, k, Sf);
  }
  k_ifft_topk<<<NB, TPB, 0, stream>>>(Sf, wk, ik);
  k_gather<<<NB * 2048, 256, 0, stream>>>((const float4*)v, wk, ik,
                                          (float4*)d_out);
}